// Round 7
// baseline (651.948 us; speedup 1.0000x reference)
//
#include <hip/hip_runtime.h>
#include <hip/hip_bf16.h>
#include <stdint.h>

// LMHA: linear multi-head attention (elu+1 feature map), S=2048 B=16 D=1024 H=8 dh=128
// Pipeline: prep_h -> pack_w -> gemm_qkv (bias+elu, s-major outs via LDS transpose
//           epilogue) -> kv_part (x4 S-split partials) -> kv_reduce -> attn_kernel
//           -> gemm_out (+bo)
// R1-R5: see git log. R5: scatter-free epilogues: qkv 598->240us (MfmaUtil 38%).
// R6: 8-phase core REGRESSED qkv 240->262 (34%): 4x more barrier crossings per MFMA
//     at 2 waves/SIMD. kv S-split x4 helped (total 685->637).
// R7: (a) revert both 256^2 cores to R5 depth-3 counted-vmcnt pipeline (verified
//     240us/38%). (b) attn den-pass reads pq tile from LDS (still resident in the
//     4 pipeline buffers after core_128<128>) instead of re-reading global: kills
//     64MB traffic + shortens per-block serial tail. (c) keep R6 kv split/reduce.

typedef __bf16 bf16x8 __attribute__((ext_vector_type(8)));
typedef float f32x4 __attribute__((ext_vector_type(4)));

#define S_LEN 2048
#define B_SZ  16
#define D_MOD 1024
#define N_H   8
#define D_H   128

__device__ __forceinline__ short f2bf(float f) {
  __bf16 b = (__bf16)f;
  return __builtin_bit_cast(short, b);
}
__device__ __forceinline__ float bf2f(short s) {
  return (float)__builtin_bit_cast(__bf16, s);
}

// async global->LDS, 16B per lane. Dest must be wave-uniform base + lane*16 (linear).
__device__ __forceinline__ void gload_lds16(const short* g, short* l) {
  __builtin_amdgcn_global_load_lds(
      (__attribute__((address_space(1))) void*)(g),
      (__attribute__((address_space(3))) void*)(l), 16, 0, 0);
}

// LDS bank swizzle for 64B rows: XOR byte bits 4-5 with row bits 1-2 (bits 7-8).
// Involution; 16-row frag reads -> 2 lanes/bank (free, m136).
__device__ __forceinline__ int swz(int o) { return o ^ (((o >> 7) & 3) << 4); }

// read bf16x8 from 8B-aligned LDS (two b64 reads)
__device__ __forceinline__ bf16x8 ld_bf8_8al(const short* p) {
  union { unsigned long long u[2]; bf16x8 v; } x;
  x.u[0] = *(const unsigned long long*)p;
  x.u[1] = *(const unsigned long long*)(p + 4);
  return x.v;
}

// ---------------- prep: h = bf16(x + pos_encoding) ----------------
__global__ void prep_h(const float* __restrict__ x, short* __restrict__ h) {
  size_t idx8 = (size_t)blockIdx.x * blockDim.x + threadIdx.x; // 8 elems / thread
  size_t base = idx8 * 8;
  int d = (int)(base & 1023);
  int r = (int)(base >> 10);
  int s = r >> 4;
  float4 v0 = *(const float4*)(x + base);
  float4 v1 = *(const float4*)(x + base + 4);
  float vs[8] = {v0.x, v0.y, v0.z, v0.w, v1.x, v1.y, v1.z, v1.w};
  const float kdiv = -9.210340371976184f / 1024.0f;
  bf16x8 ov;
#pragma unroll
  for (int t = 0; t < 8; ++t) {
    int dc = d + t;
    float div = __expf((float)(dc & ~1) * kdiv);
    float ang = (float)s * div;
    float pe = (dc & 1) ? __cosf(ang) : __sinf(ang);
    ov[t] = (__bf16)(vs[t] + pe);
  }
  *(bf16x8*)(h + base) = ov;
}

// ---------------- pack weights to bf16: [Wq;Wk;Wv;Wo] = [4096,1024] ----------------
__global__ void pack_w(const float* __restrict__ Wq, const float* __restrict__ Wk,
                       const float* __restrict__ Wv, const float* __restrict__ Wo,
                       short* __restrict__ Wcat) {
  size_t i4 = (size_t)blockIdx.x * blockDim.x + threadIdx.x;
  size_t base = i4 * 4;
  const float* src;
  size_t off;
  if (base < 1048576)      { src = Wq; off = base; }
  else if (base < 2097152) { src = Wk; off = base - 1048576; }
  else if (base < 3145728) { src = Wv; off = base - 2097152; }
  else                     { src = Wo; off = base - 3145728; }
  float4 v = *(const float4*)(src + off);
  alignas(8) short o[4] = {f2bf(v.x), f2bf(v.y), f2bf(v.z), f2bf(v.w)};
  *(uint2*)(Wcat + base) = *(const uint2*)o;
}

// ================= pipelined GEMM core, 256x256 tile, 512 thr, 8 waves (2M x 4N) ====
// Depth-3 counted-vmcnt pipeline (R5-verified): 4 LDS buffers x 32KB, one s_barrier
// per BK=32 K-tile, vmcnt(8) in main loop (3 tiles x 4 loads in flight), stage of
// tile t+3 targets buf[(t-1)&3] (reads of it retired before this iter's barrier).
template <int K>
__device__ __forceinline__ void core_256(const short* __restrict__ A,
                                         const short* __restrict__ W,
                                         char* Lb, f32x4 (&acc)[8][4]) {
  constexpr int NT = K / 32;
  static_assert(NT >= 4, "pipeline needs K >= 128");
  const int tid = threadIdx.x;
  const int lane = tid & 63;
  const int wave = tid >> 6;
  const int wm = wave & 1, wn = wave >> 1;
  const int l15 = lane & 15, quad = lane >> 4;

  const int oA0 = tid * 16, oA1 = 8192 + tid * 16;
  const int lA0 = swz(oA0), lA1 = swz(oA1);
  const short* gA0 = A + (size_t)(lA0 >> 6) * K + ((lA0 & 63) >> 1);
  const short* gA1 = A + (size_t)((lA1 - 8192) >> 6) * K + 128 * K + (((lA1 - 8192) & 63) >> 1);
  const short* gW0 = W + (size_t)(lA0 >> 6) * K + ((lA0 & 63) >> 1);
  const short* gW1 = W + (size_t)((lA1 - 8192) >> 6) * K + 128 * K + (((lA1 - 8192) & 63) >> 1);

  int rA[8], rW[4];
#pragma unroll
  for (int i = 0; i < 8; ++i)
    rA[i] = swz((wm * 128 + i * 16 + l15) * 64 + quad * 16);
#pragma unroll
  for (int j = 0; j < 4; ++j)
    rW[j] = 16384 + swz((wn * 64 + j * 16 + l15) * 64 + quad * 16);

  auto stage = [&](int t) {
    char* sb = Lb + (t & 3) * 32768;
    const int k0 = t * 32;
    gload_lds16(gA0 + k0, (short*)(sb + oA0));
    gload_lds16(gA1 + k0, (short*)(sb + oA1));
    gload_lds16(gW0 + k0, (short*)(sb + 16384 + oA0));
    gload_lds16(gW1 + k0, (short*)(sb + 16384 + oA1));
  };
  auto step = [&](int t, bool do_stage) {
    char* cb = Lb + (t & 3) * 32768;
    bf16x8 af[8], wf[4];
#pragma unroll
    for (int i = 0; i < 8; ++i) af[i] = *(const bf16x8*)(cb + rA[i]);
#pragma unroll
    for (int j = 0; j < 4; ++j) wf[j] = *(const bf16x8*)(cb + rW[j]);
    if (do_stage) stage(t + 3);
    __builtin_amdgcn_s_setprio(1);
#pragma unroll
    for (int i = 0; i < 8; ++i)
#pragma unroll
      for (int j = 0; j < 4; ++j)
        acc[i][j] = __builtin_amdgcn_mfma_f32_16x16x32_bf16(af[i], wf[j], acc[i][j], 0, 0, 0);
    __builtin_amdgcn_s_setprio(0);
    asm volatile("s_waitcnt lgkmcnt(0)" ::: "memory");
    __builtin_amdgcn_sched_barrier(0);
  };

  stage(0); stage(1); stage(2);

  for (int t = 0; t <= NT - 4; ++t) {
    asm volatile("s_waitcnt vmcnt(8)" ::: "memory");
    __builtin_amdgcn_s_barrier();
    step(t, true);
  }
  asm volatile("s_waitcnt vmcnt(8)" ::: "memory");
  __builtin_amdgcn_s_barrier();
  step(NT - 3, false);
  asm volatile("s_waitcnt vmcnt(4)" ::: "memory");
  __builtin_amdgcn_s_barrier();
  step(NT - 2, false);
  asm volatile("s_waitcnt vmcnt(0)" ::: "memory");
  __builtin_amdgcn_s_barrier();
  step(NT - 1, false);
}

// ================= pipelined GEMM core, 128x128 tile, 256 thr, 4 waves (2x2) ========
template <int K>
__device__ __forceinline__ void core_128(const short* __restrict__ A,
                                         const short* __restrict__ W,
                                         char* Lb, f32x4 (&acc)[4][4]) {
  constexpr int NT = K / 32;
  static_assert(NT >= 4, "pipeline needs K >= 128");
  const int tid = threadIdx.x;
  const int lane = tid & 63;
  const int wm = (tid >> 6) & 1, wn = tid >> 7;
  const int l15 = lane & 15, quad = lane >> 4;

  const int oA0 = tid * 16, oA1 = 4096 + tid * 16;
  const int lA0 = swz(oA0), lA1 = swz(oA1);
  const short* gA0 = A + (size_t)(lA0 >> 6) * K + ((lA0 & 63) >> 1);
  const short* gA1 = A + (size_t)((lA1 - 4096) >> 6) * K + 64 * K + (((lA1 - 4096) & 63) >> 1);
  const short* gW0 = W + (size_t)(lA0 >> 6) * K + ((lA0 & 63) >> 1);
  const short* gW1 = W + (size_t)((lA1 - 4096) >> 6) * K + 64 * K + (((lA1 - 4096) & 63) >> 1);

  int rA[4], rW[4];
#pragma unroll
  for (int i = 0; i < 4; ++i)
    rA[i] = swz((wm * 64 + i * 16 + l15) * 64 + quad * 16);
#pragma unroll
  for (int j = 0; j < 4; ++j)
    rW[j] = 8192 + swz((wn * 64 + j * 16 + l15) * 64 + quad * 16);

  auto stage = [&](int t) {
    char* sb = Lb + (t & 3) * 16384;
    const int k0 = t * 32;
    gload_lds16(gA0 + k0, (short*)(sb + oA0));
    gload_lds16(gA1 + k0, (short*)(sb + oA1));
    gload_lds16(gW0 + k0, (short*)(sb + 8192 + oA0));
    gload_lds16(gW1 + k0, (short*)(sb + 8192 + oA1));
  };
  auto step = [&](int t, bool do_stage) {
    char* cb = Lb + (t & 3) * 16384;
    bf16x8 af[4], wf[4];
#pragma unroll
    for (int i = 0; i < 4; ++i) af[i] = *(const bf16x8*)(cb + rA[i]);
#pragma unroll
    for (int j = 0; j < 4; ++j) wf[j] = *(const bf16x8*)(cb + rW[j]);
    if (do_stage) stage(t + 3);
    __builtin_amdgcn_s_setprio(1);
#pragma unroll
    for (int i = 0; i < 4; ++i)
#pragma unroll
      for (int j = 0; j < 4; ++j)
        acc[i][j] = __builtin_amdgcn_mfma_f32_16x16x32_bf16(af[i], wf[j], acc[i][j], 0, 0, 0);
    __builtin_amdgcn_s_setprio(0);
    asm volatile("s_waitcnt lgkmcnt(0)" ::: "memory");
    __builtin_amdgcn_sched_barrier(0);
  };

  stage(0); stage(1); stage(2);

  for (int t = 0; t <= NT - 4; ++t) {
    asm volatile("s_waitcnt vmcnt(8)" ::: "memory");
    __builtin_amdgcn_s_barrier();
    step(t, true);
  }
  asm volatile("s_waitcnt vmcnt(8)" ::: "memory");
  __builtin_amdgcn_s_barrier();
  step(NT - 3, false);
  asm volatile("s_waitcnt vmcnt(4)" ::: "memory");
  __builtin_amdgcn_s_barrier();
  step(NT - 2, false);
  asm volatile("s_waitcnt vmcnt(0)" ::: "memory");
  __builtin_amdgcn_s_barrier();
  step(NT - 1, false);
}

// ---------------- GEMM1: qkv = h @ Wqkv^T, fused bias + elu+1 ----------------
// Outputs ALL s-major [B,H,S,dh]: pq, pk (elu+1), pv (plain). LDS transpose epilogue.
// 2-D XCD partition (R3-verified): XCD(xm,xn) owns 32bm x 6bn, bn-fast.
__launch_bounds__(512, 2)
__global__ void gemm_qkv(const short* __restrict__ h, const short* __restrict__ Wqkv,
                         const float* __restrict__ bq, const float* __restrict__ bk,
                         const float* __restrict__ bv,
                         short* __restrict__ pq, short* __restrict__ pk,
                         short* __restrict__ pv) {
  __shared__ alignas(16) char Lb[131072];
  const int lin = blockIdx.y * 12 + blockIdx.x; // 0..1535
  const int x = lin & 7, q = lin >> 3;          // q 0..191
  const int xm = x >> 1, xn = x & 1;
  const int bm = xm * 32 + q / 6;               // 0..127
  const int bn = xn * 6 + q % 6;                // 0..11
  const int rowBase = bm * 256, colBase = bn * 256;

  f32x4 acc[8][4] = {};
  core_256<1024>(h + (size_t)rowBase * 1024, Wqkv + (size_t)colBase * 1024, Lb, acc);

  const int tid = threadIdx.x;
  const int lane = tid & 63;
  const int wave = tid >> 6;
  const int wm = wave & 1, wn = wave >> 1;
  const int l15 = lane & 15, quad = lane >> 4;

  const int p = bn >> 2; // 0:q 1:k 2:v
  const float* bias = (p == 0) ? bq : (p == 1) ? bk : bv;
  short* Pout = (p == 0) ? pq : (p == 1) ? pk : pv;

  __syncthreads(); // core fully drained on ALL waves before Lb reuse
  short* Lt = (short*)Lb; // [256][256] bf16 = 128KB
#pragma unroll
  for (int j = 0; j < 4; ++j) {
    const int c = wn * 64 + j * 16 + l15; // 0..255
    const float bval = bias[(bn & 3) * 256 + c];
#pragma unroll
    for (int i = 0; i < 8; ++i) {
#pragma unroll
      for (int r = 0; r < 4; ++r) {
        const int mloc = wm * 128 + i * 16 + quad * 4 + r;
        float v = acc[i][j][r] + bval;
        if (p < 2) v = v > 0.f ? v + 1.f : __expf(v); // elu+1 for q,k
        Lt[mloc * 256 + (c ^ ((mloc & 7) << 3))] = f2bf(v);
      }
    }
  }
  __syncthreads();
  // read-back: 512 chunks of 256B; 16 lanes cooperate per chunk -> full 64B lines.
  const int g16 = tid >> 4, L = tid & 15;
#pragma unroll
  for (int it = 0; it < 16; ++it) {
    const int chunk = it * 32 + g16;       // 0..511
    const int row = chunk >> 1, hhl = chunk & 1;
    const int grow = rowBase + row;
    const int s = grow >> 4, b = grow & 15;
    const int hh = (bn & 3) * 2 + hhl;
    const short* src = Lt + row * 256 + ((hhl * 128 + L * 8) ^ ((row & 7) << 3));
    short* dst = Pout + (((size_t)b * N_H + hh) * S_LEN + s) * D_H + L * 8;
    *(uint4*)dst = *(const uint4*)src;
  }
}

// ---------------- kv partial: kvp[bh4s][e][d] = sum_{s in split} pv[s][e]*pk[s][d] --
// S-split x4: 512 blocks (2/CU). Reg-staged transpose into [128][44] LDS, MFMA.
__launch_bounds__(256, 2)
__global__ void kv_part(const short* __restrict__ pk, const short* __restrict__ pv,
                        float* __restrict__ kvp, float* __restrict__ zp) {
  __shared__ alignas(16) short Vt[128 * 44];
  __shared__ alignas(16) short Pt[128 * 44];
  __shared__ float zl[16 * 128];
  const int split = blockIdx.x; // 0..3
  const int bh = blockIdx.y;    // 0..127
  const int sbase = split * 512;
  const short* Vg = pv + ((size_t)bh * S_LEN + sbase) * D_H;
  const short* Pg = pk + ((size_t)bh * S_LEN + sbase) * D_H;

  const int tid = threadIdx.x;
  const int lane = tid & 63;
  const int wm = (tid >> 6) & 1, wn = tid >> 7;
  const int l15 = lane & 15, quad = lane >> 4;
  const int s_loc = tid >> 3, e8 = tid & 7; // stage: s row 0..31, e-octet 0..7

  const short* vsrc = Vg + s_loc * 128 + e8 * 8;
  const short* psrc = Pg + s_loc * 128 + e8 * 8;

  f32x4 acc[4][4] = {};
  uint4 cv0, cv1, cp0, cp1;
  cv0 = *(const uint4*)(vsrc);
  cv1 = *(const uint4*)(vsrc + 64);
  cp0 = *(const uint4*)(psrc);
  cp1 = *(const uint4*)(psrc + 64);

  for (int t = 0; t < 16; ++t) {
    __builtin_amdgcn_s_barrier();
    const short* sv0 = (const short*)&cv0;
    const short* sv1 = (const short*)&cv1;
    const short* sp0 = (const short*)&cp0;
    const short* sp1 = (const short*)&cp1;
#pragma unroll
    for (int u = 0; u < 8; ++u) {
      Vt[(e8 * 8 + u) * 44 + s_loc] = sv0[u];
      Vt[(64 + e8 * 8 + u) * 44 + s_loc] = sv1[u];
      Pt[(e8 * 8 + u) * 44 + s_loc] = sp0[u];
      Pt[(64 + e8 * 8 + u) * 44 + s_loc] = sp1[u];
    }
    if (t < 15) {
      const int o = (t + 1) * 32 * 128;
      cv0 = *(const uint4*)(vsrc + o);
      cv1 = *(const uint4*)(vsrc + o + 64);
      cp0 = *(const uint4*)(psrc + o);
      cp1 = *(const uint4*)(psrc + o + 64);
    }
    asm volatile("s_waitcnt lgkmcnt(0)" ::: "memory");
    __builtin_amdgcn_sched_barrier(0);
    __builtin_amdgcn_s_barrier();
    bf16x8 af[4], wf[4];
#pragma unroll
    for (int i = 0; i < 4; ++i)
      af[i] = ld_bf8_8al(&Vt[(wm * 64 + i * 16 + l15) * 44 + quad * 8]);
#pragma unroll
    for (int j = 0; j < 4; ++j)
      wf[j] = ld_bf8_8al(&Pt[(wn * 64 + j * 16 + l15) * 44 + quad * 8]);
#pragma unroll
    for (int i = 0; i < 4; ++i)
#pragma unroll
      for (int j = 0; j < 4; ++j)
        acc[i][j] = __builtin_amdgcn_mfma_f32_16x16x32_bf16(af[i], wf[j], acc[i][j], 0, 0, 0);
    asm volatile("s_waitcnt lgkmcnt(0)" ::: "memory");
    __builtin_amdgcn_sched_barrier(0);
  }

  float* kout = kvp + (size_t)(bh * 4 + split) * (D_H * D_H);
#pragma unroll
  for (int j = 0; j < 4; ++j) {
    const int d = wn * 64 + j * 16 + l15;
#pragma unroll
    for (int i = 0; i < 4; ++i) {
#pragma unroll
      for (int r = 0; r < 4; ++r) {
        const int e = wm * 64 + i * 16 + quad * 4 + r;
        kout[(size_t)e * D_H + d] = acc[i][j][r];
      }
    }
  }
  // z partial over this split's s-range (coalesced s-major reads, L2-hot)
  __syncthreads();
  {
    const int d8 = tid & 15, so = tid >> 4; // 16 d-octets x 16 s-phases
    float za[8] = {};
    for (int s = so; s < 512; s += 16) {
      uint4 u = *(const uint4*)(Pg + (size_t)s * 128 + d8 * 8);
      const short* sp = (const short*)&u;
#pragma unroll
      for (int u2 = 0; u2 < 8; ++u2) za[u2] += bf2f(sp[u2]);
    }
#pragma unroll
    for (int u2 = 0; u2 < 8; ++u2) zl[so * 128 + d8 * 8 + u2] = za[u2];
  }
  __syncthreads();
  if (tid < 128) {
    float sum = 0.f;
#pragma unroll
    for (int k = 0; k < 16; ++k) sum += zl[k * 128 + tid];
    zp[(bh * 4 + split) * D_H + tid] = sum;
  }
}

// ---------------- kv reduce: kvT bf16 = sum of 4 partials; z likewise ----------------
__global__ void kv_reduce(const float* __restrict__ kvp, const float* __restrict__ zp,
                          short* __restrict__ kvT, float* __restrict__ z) {
  const int bh = blockIdx.x;
  const int tid = threadIdx.x; // 256
  const float* k0 = kvp + (size_t)(bh * 4) * (D_H * D_H);
  for (int i = tid; i < D_H * D_H; i += 256) {
    float s = k0[i] + k0[16384 + i] + k0[32768 + i] + k0[49152 + i];
    kvT[(size_t)bh * (D_H * D_H) + i] = f2bf(s);
  }
  if (tid < 128) {
    const float* z0 = zp + bh * 4 * D_H;
    z[bh * D_H + tid] = z0[tid] + z0[D_H + tid] + z0[2 * D_H + tid] + z0[3 * D_H + tid];
  }
}

// ---------------- num/den/divide: att = (pq @ kv) / (pq . z + eps) ----------------
// den now reads the pq tile from LDS: after core_128<128>, buffers 0..3 hold the
// 4 K-slices of the A (pq) tile (never overwritten for NT=4). A[r][c8-slice] lives
// at buf t=c8's... slice t covers k=t*32..+31; addr = t*16384 + swz(r*64 + q*16).
__launch_bounds__(256, 2)
__global__ void attn_kernel(const short* __restrict__ pq, const short* __restrict__ kvT,
                            const float* __restrict__ z, short* __restrict__ att) {
  __shared__ alignas(16) char Lb[65536];
  __shared__ float den_lds[128];
  __shared__ float z_lds[128];
  const int s0 = blockIdx.x * 128; // 16 tiles over S
  const int bh = blockIdx.y;       // 0..127
  const int tid = threadIdx.x;

  const short* Abase = pq + ((size_t)bh * S_LEN + s0) * D_H; // rows = s
  const short* Wbase = kvT + (size_t)bh * (D_H * D_H);       // rows = e, cols = d

  f32x4 acc[4][4] = {};
  core_128<128>(Abase, Wbase, Lb, acc);

  // z load AFTER core (keeps core's vmcnt counting clean)
  if (tid < 128) z_lds[tid] = z[bh * D_H + tid];
  __syncthreads();
  // den[s] = sum_d pq[s][d] * z[d] + eps -- pq read from resident LDS buffers
  if (tid < 128) {
    float sum = 0.f;
#pragma unroll
    for (int t = 0; t < 4; ++t) {
      const char* Ab = Lb + t * 16384; // A-region of buffer t = K-slice t*32..+31
#pragma unroll
      for (int c8 = 0; c8 < 2; ++c8) { // 2 x 16-short chunks per 32-k slice
        bf16x8 vv = *(const bf16x8*)(Ab + swz(tid * 64 + c8 * 32));
        bf16x8 vw = *(const bf16x8*)(Ab + swz(tid * 64 + c8 * 32 + 16));
#pragma unroll
        for (int u = 0; u < 8; ++u) {
          sum += (float)vv[u] * z_lds[t * 32 + c8 * 16 + u];
          sum += (float)vw[u] * z_lds[t * 32 + c8 * 16 + 8 + u];
        }
      }
    }
    den_lds[tid] = sum + 1e-6f;
  }
  __syncthreads();

  const int lane = tid & 63;
  const int wm = (tid >> 6) & 1, wn = tid >> 7;
  const int l15 = lane & 15, quad = lane >> 4;
  const int b = bh >> 3, hd = bh & 7;
#pragma unroll
  for (int j = 0; j < 4; ++j) {
    const int e = wn * 64 + j * 16 + l15;
#pragma unroll
    for (int i = 0; i < 4; ++i) {
#pragma unroll
      for (int r = 0; r < 4; ++r) {
        int mloc = wm * 64 + i * 16 + quad * 4 + r; // s_local
        float a = acc[i][j][r] / den_lds[mloc];
        att[((size_t)(s0 + mloc) * B_SZ + b) * D_MOD + hd * D_H + e] = f2bf(a);
      }
    }
  }
}

// ---------------- out = att @ Wo^T + bo (fp32 out), 256x256 tiles ----------------
// grid (4 bn, 128 bm). XCD x owns bm in [x*16,+16), all 4 bn (Wo 2MB L2-resident).
__launch_bounds__(512, 2)
__global__ void gemm_out(const short* __restrict__ att, const short* __restrict__ WoB,
                         const float* __restrict__ bo, float* __restrict__ out) {
  __shared__ alignas(16) char Lb[131072];
  const int lin = blockIdx.y * 4 + blockIdx.x; // 0..511
  const int x = lin & 7, q = lin >> 3;         // q 0..63
  const int bn = q & 3;                        // 0..3
  const int bm = x * 16 + (q >> 2);            // 0..127
  const int rowBase = bm * 256, colBase = bn * 256;

  f32x4 acc[8][4] = {};
  core_256<1024>(att + (size_t)rowBase * 1024, WoB + (size_t)colBase * 1024, Lb, acc);

  const int tid = threadIdx.x;
  const int lane = tid & 63;
  const int wave = tid >> 6;
  const int wm = wave & 1, wn = wave >> 1;
  const int l15 = lane & 15, quad = lane >> 4;
#pragma unroll
  for (int j = 0; j < 4; ++j) {
    const int gcol = colBase + wn * 64 + j * 16 + l15;
    const float bval = bo[gcol];
#pragma unroll
    for (int i = 0; i < 8; ++i) {
#pragma unroll
      for (int r = 0; r < 4; ++r) {
        int grow = rowBase + wm * 128 + i * 16 + quad * 4 + r;
        out[(size_t)grow * 1024 + gcol] = acc[i][j][r] + bval;
      }
    }
  }
}

extern "C" void kernel_launch(void* const* d_in, const int* in_sizes, int n_in,
                              void* d_out, int out_size, void* d_ws, size_t ws_size,
                              hipStream_t stream) {
  const float* x  = (const float*)d_in[0];
  const float* Wq = (const float*)d_in[1];
  const float* bq = (const float*)d_in[2];
  const float* Wk = (const float*)d_in[3];
  const float* bk = (const float*)d_in[4];
  const float* Wv = (const float*)d_in[5];
  const float* bv = (const float*)d_in[6];
  const float* Wo = (const float*)d_in[7];
  const float* bo = (const float*)d_in[8];
  float* out = (float*)d_out;

  char* ws = (char*)d_ws;
  short* h    = (short*)(ws);                 // 67,108,864 B (h; then kvp/zp; then att)
  short* Wcat = (short*)(ws + 67108864);      //  8,388,608 B ([Wq;Wk;Wv;Wo] bf16)
  short* pq   = (short*)(ws + 75497472);      // 67,108,864 B  [B,H,S,dh]
  short* pk   = (short*)(ws + 142606336);     // 67,108,864 B  [B,H,S,dh]
  short* pv   = (short*)(ws + 209715200);     // 67,108,864 B  [B,H,S,dh]
  short* kvT  = (short*)(ws + 276824064);     //  4,194,304 B
  float* z    = (float*)(ws + 281018368);     //     65,536 B
  // dead-h-region reuse (after gemm_qkv, before attn):
  float* kvp  = (float*)(ws);                 // 33,554,432 B fp32 partials
  float* zp   = (float*)(ws + 33554432);      //    262,144 B fp32 z partials

  prep_h<<<16384, 256, 0, stream>>>(x, h);
  pack_w<<<4096, 256, 0, stream>>>(Wq, Wk, Wv, Wo, Wcat);
  gemm_qkv<<<dim3(12, 128), 512, 0, stream>>>(h, Wcat, bq, bk, bv, pq, pk, pv);
  kv_part<<<dim3(4, 128), 256, 0, stream>>>(pk, pv, kvp, zp);
  kv_reduce<<<128, 256, 0, stream>>>(kvp, zp, kvT, z);
  attn_kernel<<<dim3(16, 128), 256, 0, stream>>>(pq, kvT, z, h /* att reuses h */);
  gemm_out<<<dim3(4, 128), 512, 0, stream>>>(h, Wcat + 3145728, bo, out);
}